// Round 7
// baseline (149.667 us; speedup 1.0000x reference)
//
#include <hip/hip_runtime.h>
#include <hip/hip_bf16.h>
#include <math.h>

#define TSEQ 2048
#define CEMB 1024
#define NHEAD 16
#define HS 64

typedef __attribute__((ext_vector_type(8))) short bf16x8;
typedef __attribute__((ext_vector_type(4))) float f32x4;
typedef __attribute__((ext_vector_type(16))) float f32x16;
typedef unsigned int u32;

__device__ __forceinline__ void gload16(const void* g, void* l) {
    __builtin_amdgcn_global_load_lds(
        (const __attribute__((address_space(1))) unsigned int*)g,
        (__attribute__((address_space(3))) unsigned int*)l, 16, 0, 0);
}

__device__ __forceinline__ u32 pk2(float a, float b) {
    union { u32 u; __hip_bfloat16 h[2]; } t;
    t.h[0] = __float2bfloat16(a); t.h[1] = __float2bfloat16(b);
    return t.u;
}

// ---------------- RoPE table ----------------
// Reference quirk: _apply_rope uses cache[:d1] where d1 = n_head after the
// transpose, so the rotation angle is head_index * theta_j (constant over t).
__global__ void rope_tbl_k(float* __restrict__ tbl) {
    int i = blockIdx.x * blockDim.x + threadIdx.x;
    if (i >= NHEAD * 32) return;
    int h = i >> 5, j = i & 31;
    double theta = pow(10000.0, -2.0 * (double)j / 1024.0);
    double ang = (double)h * theta;
    tbl[2 * i + 0] = (float)cos(ang);
    tbl[2 * i + 1] = (float)sin(ang);
}

// ---------------- fp32 -> bf16 convert (x) ----------------
__global__ __launch_bounds__(256) void cvt_bf16_k(const float* __restrict__ in,
                                                  __hip_bfloat16* __restrict__ out) {
    int i = (blockIdx.x * 256 + threadIdx.x) * 8;
    float4 a = *(const float4*)(in + i);
    float4 b = *(const float4*)(in + i + 4);
    union { bf16x8 v; __hip_bfloat16 h[8]; } pk;
    pk.h[0] = __float2bfloat16(a.x); pk.h[1] = __float2bfloat16(a.y);
    pk.h[2] = __float2bfloat16(a.z); pk.h[3] = __float2bfloat16(a.w);
    pk.h[4] = __float2bfloat16(b.x); pk.h[5] = __float2bfloat16(b.y);
    pk.h[6] = __float2bfloat16(b.z); pk.h[7] = __float2bfloat16(b.w);
    *(bf16x8*)(out + i) = pk.v;
}

// ---------------- transpose fp32 (K,N) -> bf16 (N,K) ----------------
__global__ __launch_bounds__(256) void transpose_bf16_k(const float* __restrict__ src,
                                                        __hip_bfloat16* __restrict__ dst,
                                                        int K, int N) {
    __shared__ float tile[32][33];
    int n0 = blockIdx.x * 32, k0 = blockIdx.y * 32;
    int tx = threadIdx.x & 31, ty = threadIdx.x >> 5;   // ty 0..7
#pragma unroll
    for (int i = 0; i < 32; i += 8)
        tile[ty + i][tx] = src[(size_t)(k0 + ty + i) * N + n0 + tx];
    __syncthreads();
#pragma unroll
    for (int i = 0; i < 32; i += 8)
        dst[(size_t)(n0 + ty + i) * K + k0 + tx] = __float2bfloat16(tile[tx][ty + i]);
}

// ---------------- QKV GEMM, bf16 MFMA, RoPE epilogue ----------------
// 128x128 tile, 4 waves (2x2), 4x4 16x16x32 frags, BK=32, double-buffered
// global_load_lds prefetch (issue t+1, compute t, ONE barrier per step).
__global__ __launch_bounds__(256) void qkv_mfma_k(
    const __hip_bfloat16* __restrict__ Xb, const __hip_bfloat16* __restrict__ Wt,
    const float* __restrict__ bias, const float* __restrict__ tbl,
    __hip_bfloat16* __restrict__ Qb, __hip_bfloat16* __restrict__ Kb,
    __hip_bfloat16* __restrict__ Vtb)
{
    __shared__ __hip_bfloat16 Al[2][128 * 32];
    __shared__ __hip_bfloat16 Bl[2][128 * 32];
    const int tid = threadIdx.x;
    const int lane = tid & 63, w = tid >> 6;
    const int lr = lane & 15, lg = lane >> 4;
    const int wm = w >> 1, wn = w & 1;
    const int n0 = blockIdx.x * 128;   // 0..2944
    const int m0 = blockIdx.y * 128;   // 0..3968
    const __hip_bfloat16* gA = Xb + (size_t)(m0 + (tid >> 2)) * CEMB + (tid & 3) * 8;
    const __hip_bfloat16* gB = Wt + (size_t)(n0 + (tid >> 2)) * CEMB + (tid & 3) * 8;
#define QSTAGE(buf, kk) do { \
        gload16(gA + (kk), &Al[buf][tid * 8]); \
        gload16(gA + 64 * CEMB + (kk), &Al[buf][2048 + tid * 8]); \
        gload16(gB + (kk), &Bl[buf][tid * 8]); \
        gload16(gB + 64 * CEMB + (kk), &Bl[buf][2048 + tid * 8]); } while (0)
    f32x4 acc[4][4] = {};
    QSTAGE(0, 0);
    __syncthreads();
    for (int k0 = 0; k0 < CEMB; k0 += 32) {
        const int cur = (k0 >> 5) & 1;
        if (k0 + 32 < CEMB) QSTAGE(cur ^ 1, k0 + 32);
        bf16x8 af[4], bfr[4];
#pragma unroll
        for (int mi = 0; mi < 4; ++mi)
            af[mi] = *(const bf16x8*)&Al[cur][(wm * 64 + mi * 16 + lr) * 32 + lg * 8];
#pragma unroll
        for (int ni = 0; ni < 4; ++ni)
            bfr[ni] = *(const bf16x8*)&Bl[cur][(wn * 64 + ni * 16 + lr) * 32 + lg * 8];
#pragma unroll
        for (int mi = 0; mi < 4; ++mi)
#pragma unroll
            for (int ni = 0; ni < 4; ++ni)
                acc[mi][ni] = __builtin_amdgcn_mfma_f32_16x16x32_bf16(af[mi], bfr[ni], acc[mi][ni], 0, 0, 0);
        __syncthreads();
    }
    // epilogue: bias + rope + scatter. sec/bb uniform per block.
    const int sec = (n0 >> 10);
#pragma unroll
    for (int mi = 0; mi < 4; ++mi) {
#pragma unroll
        for (int ni = 0; ni < 4; ++ni) {
            const int gcol = n0 + wn * 64 + ni * 16 + lr;
            const int c63 = gcol & 63;
            const int h = (gcol & 1023) >> 6;
            const int j = c63 >> 1;
            const float cth = tbl[(h * 32 + j) * 2 + 0];
            const float sth = tbl[(h * 32 + j) * 2 + 1];
            const float bv = bias[gcol];
            const int growb = m0 + wm * 64 + mi * 16 + lg * 4;
            const int bb = growb >> 11;
            const int t0 = growb & 2047;
            if (sec == 2) {
                union { unsigned long long u; __hip_bfloat16 hh[4]; } pk;
#pragma unroll
                for (int r = 0; r < 4; ++r) pk.hh[r] = __float2bfloat16(acc[mi][ni][r] + bv);
                *(unsigned long long*)&Vtb[(((size_t)bb * NHEAD + h) * HS + c63) * TSEQ + t0] = pk.u;
            } else {
                // Q scale folds 1/sqrt(hs) AND log2(e) so attention can use exp2
                const float sc = (sec == 0) ? 0.18033688011112042f : 1.0f;
                __hip_bfloat16* dst = (sec == 0) ? Qb : Kb;
#pragma unroll
                for (int r = 0; r < 4; ++r) {
                    float val = acc[mi][ni][r] + bv;
                    float prt = __shfl_xor(val, 1);
                    float rot = (lr & 1) ? (val * cth + prt * sth) : (val * cth - prt * sth);
                    dst[(((size_t)bb * NHEAD + h) * TSEQ + t0 + r) * HS + c63] = __float2bfloat16(rot * sc);
                }
            }
        }
    }
#undef QSTAGE
}

// ---------------- Flash attention, swapped-QK^T 32x32 MFMA ----------------
// Block = 2 waves x 32 q-rows. Grid flat 1024: bh = id&31 (CU balance + XCD
// L2 locality), qb = id>>5. S^T = mfma32(K,Q): lane&31 = q, softmax fully
// in-register (tree + one shfl_xor(32)); P -> bf16 pairs + 8 word-exchanges
// feed PV's B-operand directly (no P LDS roundtrip). O^T = mfma32(V^T, P^T).
// Dbuf global_load_lds staging with pre-swizzled source (T21), XOR swizzle
// ((row^(row>>3))&7)<<4. Epilogue: LDS transpose -> coalesced bf16x8 stores.
__global__ __launch_bounds__(128) void attn_k(
    const __hip_bfloat16* __restrict__ Q, const __hip_bfloat16* __restrict__ K,
    const __hip_bfloat16* __restrict__ Vt, __hip_bfloat16* __restrict__ Y)
{
    __shared__ __hip_bfloat16 KsBuf[2][64 * 64];   // [kv][hs], swizzled storage
    __shared__ __hip_bfloat16 VsBuf[2][64 * 64];   // [hs][kv], swizzled storage
    const int tid = threadIdx.x;                   // 0..127
    const int w = tid >> 6;
    const int lane = tid & 63;
    const int l31 = lane & 31;
    const int hi = lane >> 5;
    const int id = blockIdx.x;
    const int bh = id & 31;
    const int qb = id >> 5;                        // 0..31
    const size_t bho = (size_t)bh * TSEQ * HS;
    const int qw = qb * 64 + w * 32;

    // staging: 1024 chunks16/tile (K+V), thread t owns chunks t+128j.
    // LDS dest linear; global source pre-permuted by the inverse XOR swizzle.
    int srcK[4], srcV[4];
#pragma unroll
    for (int j = 0; j < 4; ++j) {
        int L = (tid + 128 * j) * 16;
        int row = L >> 7;
        int ce = ((L & 127) ^ (((row ^ (row >> 3)) & 7) << 4)) >> 1;
        srcK[j] = row * HS + ce;
        srcV[j] = row * TSEQ + ce;
    }
    const __hip_bfloat16* Kg = K + bho;
    const __hip_bfloat16* Vg = Vt + bho;
#define ASTAGE(buf, kt_) do { \
        const __hip_bfloat16* kg_ = Kg + (size_t)(kt_) * 64 * HS; \
        const __hip_bfloat16* vg_ = Vg + (size_t)(kt_) * 64; \
        char* kb_ = (char*)KsBuf[buf]; char* vb_ = (char*)VsBuf[buf]; \
        _Pragma("unroll") \
        for (int j = 0; j < 4; ++j) { \
            gload16(kg_ + srcK[j], kb_ + (tid + 128 * j) * 16); \
            gload16(vg_ + srcV[j], vb_ + (tid + 128 * j) * 16); } } while (0)

    // Q B-fragments (col = q = l31, k = hi*8+i per 16-wide hs slice)
    bf16x8 qf[4];
    {
        const __hip_bfloat16* qp = Q + bho + (size_t)(qw + l31) * HS + hi * 8;
#pragma unroll
        for (int kb = 0; kb < 4; ++kb) qf[kb] = *(const bf16x8*)(qp + kb * 16);
    }
    // per-lane swizzled LDS row bases (rows l31 and 32+l31)
    const int base0 = l31 * 128;
    const int swz0 = ((l31 ^ (l31 >> 3)) & 7) << 4;
    const int r32 = 32 + l31;
    const int base1 = r32 * 128;
    const int swz1 = ((r32 ^ (r32 >> 3)) & 7) << 4;

    float mrow = -1e30f, lsum = 0.f;
    f32x16 o0 = {}, o1 = {};   // O^T: col=q=l31, row d = crow(r,hi) + 32*dt

    ASTAGE(0, 0);
    __syncthreads();
    for (int kt = 0; kt <= qb; ++kt) {
        const int cur = kt & 1;
        if (kt < qb) ASTAGE(cur ^ 1, kt + 1);   // flies under this tile's compute
        const char* KsB = (const char*)KsBuf[cur];
        const char* VsB = (const char*)VsBuf[cur];
        const bool do1 = (w == 1) || (kt < qb);  // kv subtile 1 not fully masked
        // S^T = K * Q  (A=K: row=kv, B=Q: col=q)
        f32x16 s0 = {}, s1 = {};
#pragma unroll
        for (int kb = 0; kb < 4; ++kb) {
            bf16x8 kf = *(const bf16x8*)(KsB + base0 + ((kb * 32 + hi * 16) ^ swz0));
            s0 = __builtin_amdgcn_mfma_f32_32x32x16_bf16(kf, qf[kb], s0, 0, 0, 0);
        }
        if (do1) {
#pragma unroll
            for (int kb = 0; kb < 4; ++kb) {
                bf16x8 kf = *(const bf16x8*)(KsB + base1 + ((kb * 32 + hi * 16) ^ swz1));
                s1 = __builtin_amdgcn_mfma_f32_32x32x16_bf16(kf, qf[kb], s1, 0, 0, 0);
            }
        }
        // causal mask: only the sub==w subtile of the diagonal tile masks
        if (kt == qb) {
            if (w == 0) {
#pragma unroll
                for (int r = 0; r < 16; ++r) {
                    int crow = (r & 3) + 8 * (r >> 2) + 4 * hi;
                    if (crow > l31) s0[r] = -1e30f;
                }
            } else {
#pragma unroll
                for (int r = 0; r < 16; ++r) {
                    int crow = (r & 3) + 8 * (r >> 2) + 4 * hi;
                    if (crow > l31) s1[r] = -1e30f;
                }
            }
        }
        // in-register online softmax for q = l31 (partner lane^32 mirrors)
        float mx = s0[0];
#pragma unroll
        for (int r = 1; r < 16; ++r) mx = fmaxf(mx, s0[r]);
        if (do1) {
#pragma unroll
            for (int r = 0; r < 16; ++r) mx = fmaxf(mx, s1[r]);
        }
        mx = fmaxf(mx, __shfl_xor(mx, 32));
        const float mn = fmaxf(mrow, mx);
        const float alpha = __builtin_amdgcn_exp2f(mrow - mn);
        mrow = mn;
        float ls = 0.f;
#pragma unroll
        for (int r = 0; r < 16; ++r) { s0[r] = __builtin_amdgcn_exp2f(s0[r] - mn); ls += s0[r]; }
        if (do1) {
#pragma unroll
            for (int r = 0; r < 16; ++r) { s1[r] = __builtin_amdgcn_exp2f(s1[r] - mn); ls += s1[r]; }
        }
        ls += __shfl_xor(ls, 32);
        lsum = lsum * alpha + ls;
        o0 = o0 * alpha;
        o1 = o1 * alpha;
        // pack P to bf16 pairs + lane^32 word exchange -> PV B-frags pa[ks]
        union { u32 u[4]; bf16x8 v; } pa[4];
        {
            u32 w01 = pk2(s0[0], s0[1]),   w23 = pk2(s0[2], s0[3]);
            u32 w45 = pk2(s0[4], s0[5]),   w67 = pk2(s0[6], s0[7]);
            u32 w89 = pk2(s0[8], s0[9]),   wab = pk2(s0[10], s0[11]);
            u32 wcd = pk2(s0[12], s0[13]), wef = pk2(s0[14], s0[15]);
            u32 xa = __shfl_xor(hi ? w01 : w45, 32);
            u32 xb = __shfl_xor(hi ? w23 : w67, 32);
            u32 xc = __shfl_xor(hi ? w89 : wcd, 32);
            u32 xd = __shfl_xor(hi ? wab : wef, 32);
            if (hi == 0) {
                pa[0].u[0] = w01; pa[0].u[1] = w23; pa[0].u[2] = xa;  pa[0].u[3] = xb;
                pa[1].u[0] = w89; pa[1].u[1] = wab; pa[1].u[2] = xc;  pa[1].u[3] = xd;
            } else {
                pa[0].u[0] = xa;  pa[0].u[1] = xb;  pa[0].u[2] = w45; pa[0].u[3] = w67;
                pa[1].u[0] = xc;  pa[1].u[1] = xd;  pa[1].u[2] = wcd; pa[1].u[3] = wef;
            }
        }
        if (do1) {
            u32 w01 = pk2(s1[0], s1[1]),   w23 = pk2(s1[2], s1[3]);
            u32 w45 = pk2(s1[4], s1[5]),   w67 = pk2(s1[6], s1[7]);
            u32 w89 = pk2(s1[8], s1[9]),   wab = pk2(s1[10], s1[11]);
            u32 wcd = pk2(s1[12], s1[13]), wef = pk2(s1[14], s1[15]);
            u32 xa = __shfl_xor(hi ? w01 : w45, 32);
            u32 xb = __shfl_xor(hi ? w23 : w67, 32);
            u32 xc = __shfl_xor(hi ? w89 : wcd, 32);
            u32 xd = __shfl_xor(hi ? wab : wef, 32);
            if (hi == 0) {
                pa[2].u[0] = w01; pa[2].u[1] = w23; pa[2].u[2] = xa;  pa[2].u[3] = xb;
                pa[3].u[0] = w89; pa[3].u[1] = wab; pa[3].u[2] = xc;  pa[3].u[3] = xd;
            } else {
                pa[2].u[0] = xa;  pa[2].u[1] = xb;  pa[2].u[2] = w45; pa[2].u[3] = w67;
                pa[3].u[0] = xc;  pa[3].u[1] = xd;  pa[3].u[2] = wcd; pa[3].u[3] = wef;
            }
        }
        // PV: O^T += V^T * P^T  (A=V^T: row=d, B=P^T: col=q)
#pragma unroll
        for (int ks = 0; ks < 2; ++ks) {
            bf16x8 vf0 = *(const bf16x8*)(VsB + base0 + ((ks * 32 + hi * 16) ^ swz0));
            o0 = __builtin_amdgcn_mfma_f32_32x32x16_bf16(vf0, pa[ks].v, o0, 0, 0, 0);
            bf16x8 vf1 = *(const bf16x8*)(VsB + base1 + ((ks * 32 + hi * 16) ^ swz1));
            o1 = __builtin_amdgcn_mfma_f32_32x32x16_bf16(vf1, pa[ks].v, o1, 0, 0, 0);
        }
        if (do1) {
#pragma unroll
            for (int ks = 2; ks < 4; ++ks) {
                bf16x8 vf0 = *(const bf16x8*)(VsB + base0 + ((ks * 32 + hi * 16) ^ swz0));
                o0 = __builtin_amdgcn_mfma_f32_32x32x16_bf16(vf0, pa[ks].v, o0, 0, 0, 0);
                bf16x8 vf1 = *(const bf16x8*)(VsB + base1 + ((ks * 32 + hi * 16) ^ swz1));
                o1 = __builtin_amdgcn_mfma_f32_32x32x16_bf16(vf1, pa[ks].v, o1, 0, 0, 0);
            }
        }
        __syncthreads();   // drains prefetch vmcnt + guards buffer reuse
    }
    // epilogue: transpose O^T via LDS (per-wave region), coalesced Y stores
    __syncthreads();
    {
        char* T = (char*)KsBuf[0] + w * 4096;      // [32 q][64 d] bf16, swizzled
        const float inv = 1.f / lsum;
        const int tsw = (l31 & 7) << 4;
#pragma unroll
        for (int r = 0; r < 16; ++r) {
            int d0 = (r & 3) + 8 * (r >> 2) + 4 * hi;
            *(__hip_bfloat16*)(T + base0 + ((d0 * 2) ^ tsw)) = __float2bfloat16(o0[r] * inv);
            *(__hip_bfloat16*)(T + base0 + (((d0 + 32) * 2) ^ tsw)) = __float2bfloat16(o1[r] * inv);
        }
        const int b = bh >> 4, h = bh & 15;
#pragma unroll
        for (int p = 0; p < 4; ++p) {
            int q = p * 8 + (lane >> 3);
            int colb = ((lane & 7) * 16) ^ ((q & 7) << 4);
            bf16x8 v = *(const bf16x8*)(T + q * 128 + colb);
            *(bf16x8*)(Y + ((size_t)b * TSEQ + qw + q) * CEMB + h * HS + (lane & 7) * 8) = v;
        }
    }
#undef ASTAGE
}

// ---------------- Output projection, bf16 MFMA ----------------
__global__ __launch_bounds__(256) void proj_mfma_k(
    const __hip_bfloat16* __restrict__ Ab, const __hip_bfloat16* __restrict__ Wt,
    const float* __restrict__ bias, float* __restrict__ out)
{
    __shared__ __hip_bfloat16 Al[2][128 * 32];
    __shared__ __hip_bfloat16 Bl[2][128 * 32];
    const int tid = threadIdx.x;
    const int lane = tid & 63, w = tid >> 6;
    const int lr = lane & 15, lg = lane >> 4;
    const int wm = w >> 1, wn = w & 1;
    const int n0 = blockIdx.x * 128;
    const int m0 = blockIdx.y * 128;
    const __hip_bfloat16* gA = Ab + (size_t)(m0 + (tid >> 2)) * CEMB + (tid & 3) * 8;
    const __hip_bfloat16* gB = Wt + (size_t)(n0 + (tid >> 2)) * CEMB + (tid & 3) * 8;
#define PSTAGE(buf, kk) do { \
        gload16(gA + (kk), &Al[buf][tid * 8]); \
        gload16(gA + 64 * CEMB + (kk), &Al[buf][2048 + tid * 8]); \
        gload16(gB + (kk), &Bl[buf][tid * 8]); \
        gload16(gB + 64 * CEMB + (kk), &Bl[buf][2048 + tid * 8]); } while (0)
    f32x4 acc[4][4] = {};
    PSTAGE(0, 0);
    __syncthreads();
    for (int k0 = 0; k0 < CEMB; k0 += 32) {
        const int cur = (k0 >> 5) & 1;
        if (k0 + 32 < CEMB) PSTAGE(cur ^ 1, k0 + 32);
        bf16x8 af[4], bfr[4];
#pragma unroll
        for (int mi = 0; mi < 4; ++mi)
            af[mi] = *(const bf16x8*)&Al[cur][(wm * 64 + mi * 16 + lr) * 32 + lg * 8];
#pragma unroll
        for (int ni = 0; ni < 4; ++ni)
            bfr[ni] = *(const bf16x8*)&Bl[cur][(wn * 64 + ni * 16 + lr) * 32 + lg * 8];
#pragma unroll
        for (int mi = 0; mi < 4; ++mi)
#pragma unroll
            for (int ni = 0; ni < 4; ++ni)
                acc[mi][ni] = __builtin_amdgcn_mfma_f32_16x16x32_bf16(af[mi], bfr[ni], acc[mi][ni], 0, 0, 0);
        __syncthreads();
    }
#pragma unroll
    for (int mi = 0; mi < 4; ++mi) {
#pragma unroll
        for (int ni = 0; ni < 4; ++ni) {
            const int gcol = n0 + wn * 64 + ni * 16 + lr;
            const float bv = bias[gcol];
            const int growb = m0 + wm * 64 + mi * 16 + lg * 4;
#pragma unroll
            for (int r = 0; r < 4; ++r)
                out[(size_t)(growb + r) * CEMB + gcol] = acc[mi][ni][r] + bv;
        }
    }
#undef PSTAGE
}

extern "C" void kernel_launch(void* const* d_in, const int* in_sizes, int n_in,
                              void* d_out, int out_size, void* d_ws, size_t ws_size,
                              hipStream_t stream)
{
    const float* x      = (const float*)d_in[0];
    const float* w_attn = (const float*)d_in[1];
    const float* b_attn = (const float*)d_in[2];
    const float* w_proj = (const float*)d_in[3];
    const float* b_proj = (const float*)d_in[4];
    float* out = (float*)d_out;
    char* base = (char*)d_ws;

    const size_t MB = 1048576;
    float* tbl          = (float*)base;                         // 4 KB
    __hip_bfloat16* Xb  = (__hip_bfloat16*)(base + 4096);       // 8 MB (reused as Yb)
    __hip_bfloat16* Wta = (__hip_bfloat16*)(base + 4096 + 8 * MB);   // 6 MB
    __hip_bfloat16* Wpt = (__hip_bfloat16*)(base + 4096 + 14 * MB);  // 2 MB
    __hip_bfloat16* Qb  = (__hip_bfloat16*)(base + 4096 + 16 * MB);  // 8 MB
    __hip_bfloat16* Kb  = (__hip_bfloat16*)(base + 4096 + 24 * MB);  // 8 MB
    __hip_bfloat16* Vtb = (__hip_bfloat16*)(base + 4096 + 32 * MB);  // 8 MB
    __hip_bfloat16* Yb  = Xb;   // x no longer needed after qkv GEMM

    rope_tbl_k<<<1, 512, 0, stream>>>(tbl);
    cvt_bf16_k<<<2048, 256, 0, stream>>>(x, Xb);
    transpose_bf16_k<<<dim3(96, 32), 256, 0, stream>>>(w_attn, Wta, CEMB, 3 * CEMB);
    transpose_bf16_k<<<dim3(32, 32), 256, 0, stream>>>(w_proj, Wpt, CEMB, CEMB);
    qkv_mfma_k<<<dim3(24, 32), 256, 0, stream>>>(Xb, Wta, b_attn, tbl, Qb, Kb, Vtb);
    attn_k<<<1024, 128, 0, stream>>>(Qb, Kb, Vtb, Yb);
    proj_mfma_k<<<dim3(8, 32), 256, 0, stream>>>(Yb, Wpt, b_proj, out);
}

// Round 9
// 147.641 us; speedup vs baseline: 1.0137x; 1.0137x over previous
//
#include <hip/hip_runtime.h>
#include <hip/hip_bf16.h>
#include <math.h>

#define TSEQ 2048
#define CEMB 1024
#define NHEAD 16
#define HS 64

typedef __attribute__((ext_vector_type(8))) short bf16x8;
typedef __attribute__((ext_vector_type(4))) float f32x4;
typedef __attribute__((ext_vector_type(16))) float f32x16;
typedef unsigned int u32;
typedef unsigned long long u64;

__device__ __forceinline__ void gload16(const void* g, void* l) {
    __builtin_amdgcn_global_load_lds(
        (const __attribute__((address_space(1))) unsigned int*)g,
        (__attribute__((address_space(3))) unsigned int*)l, 16, 0, 0);
}

__device__ __forceinline__ u32 pk2(float a, float b) {
    union { u32 u; __hip_bfloat16 h[2]; } t;
    t.h[0] = __float2bfloat16(a); t.h[1] = __float2bfloat16(b);
    return t.u;
}

// ---------------- RoPE table ----------------
// Reference quirk: _apply_rope uses cache[:d1] where d1 = n_head after the
// transpose, so the rotation angle is head_index * theta_j (constant over t).
__global__ void rope_tbl_k(float* __restrict__ tbl) {
    int i = blockIdx.x * blockDim.x + threadIdx.x;
    if (i >= NHEAD * 32) return;
    int h = i >> 5, j = i & 31;
    double theta = pow(10000.0, -2.0 * (double)j / 1024.0);
    double ang = (double)h * theta;
    tbl[2 * i + 0] = (float)cos(ang);
    tbl[2 * i + 1] = (float)sin(ang);
}

// ---------------- fp32 -> bf16 convert (x) ----------------
__global__ __launch_bounds__(256) void cvt_bf16_k(const float* __restrict__ in,
                                                  __hip_bfloat16* __restrict__ out) {
    int i = (blockIdx.x * 256 + threadIdx.x) * 8;
    float4 a = *(const float4*)(in + i);
    float4 b = *(const float4*)(in + i + 4);
    union { bf16x8 v; __hip_bfloat16 h[8]; } pk;
    pk.h[0] = __float2bfloat16(a.x); pk.h[1] = __float2bfloat16(a.y);
    pk.h[2] = __float2bfloat16(a.z); pk.h[3] = __float2bfloat16(a.w);
    pk.h[4] = __float2bfloat16(b.x); pk.h[5] = __float2bfloat16(b.y);
    pk.h[6] = __float2bfloat16(b.z); pk.h[7] = __float2bfloat16(b.w);
    *(bf16x8*)(out + i) = pk.v;
}

// ---------------- transpose fp32 (K,N) -> bf16 (N,K) ----------------
__global__ __launch_bounds__(256) void transpose_bf16_k(const float* __restrict__ src,
                                                        __hip_bfloat16* __restrict__ dst,
                                                        int K, int N) {
    __shared__ float tile[32][33];
    int n0 = blockIdx.x * 32, k0 = blockIdx.y * 32;
    int tx = threadIdx.x & 31, ty = threadIdx.x >> 5;   // ty 0..7
#pragma unroll
    for (int i = 0; i < 32; i += 8)
        tile[ty + i][tx] = src[(size_t)(k0 + ty + i) * N + n0 + tx];
    __syncthreads();
#pragma unroll
    for (int i = 0; i < 32; i += 8)
        dst[(size_t)(n0 + ty + i) * K + k0 + tx] = __float2bfloat16(tile[tx][ty + i]);
}

// ---------------- QKV GEMM, bf16 MFMA, RoPE epilogue ----------------
// 128x128 tile, 4 waves (2x2), 4x4 16x16x32 frags, BK=32, double-buffered
// global_load_lds prefetch. V-section epilogue transposes via LDS so the
// (b,h,hs,T) scatter becomes coalesced 16B stores (was 2B x 4KB-stride).
__global__ __launch_bounds__(256) void qkv_mfma_k(
    const __hip_bfloat16* __restrict__ Xb, const __hip_bfloat16* __restrict__ Wt,
    const float* __restrict__ bias, const float* __restrict__ tbl,
    __hip_bfloat16* __restrict__ Qb, __hip_bfloat16* __restrict__ Kb,
    __hip_bfloat16* __restrict__ Vtb)
{
    __shared__ __hip_bfloat16 SM[4][128 * 32];   // A dbuf = SM[0..1], B dbuf = SM[2..3]
    const int tid = threadIdx.x;
    const int lane = tid & 63, w = tid >> 6;
    const int lr = lane & 15, lg = lane >> 4;
    const int wm = w >> 1, wn = w & 1;
    const int n0 = blockIdx.x * 128;   // 0..2944
    const int m0 = blockIdx.y * 128;   // 0..3968
    const __hip_bfloat16* gA = Xb + (size_t)(m0 + (tid >> 2)) * CEMB + (tid & 3) * 8;
    const __hip_bfloat16* gB = Wt + (size_t)(n0 + (tid >> 2)) * CEMB + (tid & 3) * 8;
#define QSTAGE(buf, kk) do { \
        gload16(gA + (kk), &SM[buf][tid * 8]); \
        gload16(gA + 64 * CEMB + (kk), &SM[buf][2048 + tid * 8]); \
        gload16(gB + (kk), &SM[2 + (buf)][tid * 8]); \
        gload16(gB + 64 * CEMB + (kk), &SM[2 + (buf)][2048 + tid * 8]); } while (0)
    f32x4 acc[4][4] = {};
    QSTAGE(0, 0);
    __syncthreads();
    for (int k0 = 0; k0 < CEMB; k0 += 32) {
        const int cur = (k0 >> 5) & 1;
        if (k0 + 32 < CEMB) QSTAGE(cur ^ 1, k0 + 32);
        bf16x8 af[4], bfr[4];
#pragma unroll
        for (int mi = 0; mi < 4; ++mi)
            af[mi] = *(const bf16x8*)&SM[cur][(wm * 64 + mi * 16 + lr) * 32 + lg * 8];
#pragma unroll
        for (int ni = 0; ni < 4; ++ni)
            bfr[ni] = *(const bf16x8*)&SM[2 + cur][(wn * 64 + ni * 16 + lr) * 32 + lg * 8];
#pragma unroll
        for (int mi = 0; mi < 4; ++mi)
#pragma unroll
            for (int ni = 0; ni < 4; ++ni)
                acc[mi][ni] = __builtin_amdgcn_mfma_f32_16x16x32_bf16(af[mi], bfr[ni], acc[mi][ni], 0, 0, 0);
        __syncthreads();
    }
    const int sec = (n0 >> 10);
    const int bb = m0 >> 11;
    const int t0v = m0 & 2047;          // batch-local sequence base (FIX: was m0)
    if (sec == 2) {
        // V: bias -> LDS transpose (swizzled) -> coalesced stores to (b,h,hs,T)
        char* T = (char*)SM;   // [128 n][128 m] bf16, row stride 256B
#pragma unroll
        for (int mi = 0; mi < 4; ++mi) {
#pragma unroll
            for (int ni = 0; ni < 4; ++ni) {
                const int nl = wn * 64 + ni * 16 + lr;
                const float bv = bias[n0 + nl];
                const int mb = wm * 64 + mi * 16 + lg * 4;
                union { u64 u; __hip_bfloat16 hh[4]; } pk;
#pragma unroll
                for (int r = 0; r < 4; ++r) pk.hh[r] = __float2bfloat16(acc[mi][ni][r] + bv);
                *(u64*)(T + nl * 256 + ((mb * 2) ^ ((nl & 7) << 4))) = pk.u;
            }
        }
        __syncthreads();
        const int h0 = (n0 & 1023) >> 6;
#pragma unroll
        for (int i = 0; i < 8; ++i) {
            int cid = tid + 256 * i;
            int n = cid >> 4, mc = cid & 15;
            bf16x8 v = *(const bf16x8*)(T + n * 256 + ((mc * 16) ^ ((n & 7) << 4)));
            *(bf16x8*)&Vtb[(((size_t)bb * NHEAD + h0 + (n >> 6)) * HS + (n & 63)) * TSEQ + t0v + mc * 8] = v;
        }
    } else {
        // Q/K: bias + rope, grouped stores (t0+r rows, 16-lane contiguous cols)
#pragma unroll
        for (int mi = 0; mi < 4; ++mi) {
#pragma unroll
            for (int ni = 0; ni < 4; ++ni) {
                const int gcol = n0 + wn * 64 + ni * 16 + lr;
                const int c63 = gcol & 63;
                const int h = (gcol & 1023) >> 6;
                const int j = c63 >> 1;
                const float cth = tbl[(h * 32 + j) * 2 + 0];
                const float sth = tbl[(h * 32 + j) * 2 + 1];
                const float bv = bias[gcol];
                const int growb = m0 + wm * 64 + mi * 16 + lg * 4;
                const int t0 = growb & 2047;
                // Q scale folds 1/sqrt(hs) AND log2(e) so attention can use exp2
                const float sc = (sec == 0) ? 0.18033688011112042f : 1.0f;
                __hip_bfloat16* dst = (sec == 0) ? Qb : Kb;
#pragma unroll
                for (int r = 0; r < 4; ++r) {
                    float val = acc[mi][ni][r] + bv;
                    float prt = __shfl_xor(val, 1);
                    float rot = (lr & 1) ? (val * cth + prt * sth) : (val * cth - prt * sth);
                    dst[(((size_t)bb * NHEAD + h) * TSEQ + t0 + r) * HS + c63] = __float2bfloat16(rot * sc);
                }
            }
        }
    }
#undef QSTAGE
}

// ---------------- Flash attention, swapped-QK^T 32x32 MFMA ----------------
// Block = 2 waves x 32 q-rows. Grid flat 1024: bh = id&31 (XCD L2 locality),
// g = id>>5 remapped so each CU's four qbs sum to exactly 66 tiles (flat
// makespan; was 52..80). S^T = mfma32(K,Q), in-register softmax, P packed
// in-register -> PV B-frags, O^T = mfma32(V^T,P^T). Dbuf gload_lds staging,
// pre-swizzled source (T21). setprio(1) around MFMA clusters (T5).
__global__ __launch_bounds__(128) void attn_k(
    const __hip_bfloat16* __restrict__ Q, const __hip_bfloat16* __restrict__ K,
    const __hip_bfloat16* __restrict__ Vt, __hip_bfloat16* __restrict__ Y)
{
    __shared__ __hip_bfloat16 KsBuf[2][64 * 64];   // [kv][hs], swizzled storage
    __shared__ __hip_bfloat16 VsBuf[2][64 * 64];   // [hs][kv], swizzled storage
    const int tid = threadIdx.x;                   // 0..127
    const int w = tid >> 6;
    const int lane = tid & 63;
    const int l31 = lane & 31;
    const int hi = lane >> 5;
    const int id = blockIdx.x;
    const int bh = id & 31;
    // load-flattening remap: CU gets {a,15-a,16+a,31-a} -> 66 tiles each
    const int g = id >> 5, ga = g & 7, gb = g >> 3;
    const int qb = gb * 8 + ((gb & 1) ? (7 - ga) : ga);
    const size_t bho = (size_t)bh * TSEQ * HS;
    const int qw = qb * 64 + w * 32;

    int srcK[4], srcV[4];
#pragma unroll
    for (int j = 0; j < 4; ++j) {
        int L = (tid + 128 * j) * 16;
        int row = L >> 7;
        int ce = ((L & 127) ^ (((row ^ (row >> 3)) & 7) << 4)) >> 1;
        srcK[j] = row * HS + ce;
        srcV[j] = row * TSEQ + ce;
    }
    const __hip_bfloat16* Kg = K + bho;
    const __hip_bfloat16* Vg = Vt + bho;
#define ASTAGE(buf, kt_) do { \
        const __hip_bfloat16* kg_ = Kg + (size_t)(kt_) * 64 * HS; \
        const __hip_bfloat16* vg_ = Vg + (size_t)(kt_) * 64; \
        char* kb_ = (char*)KsBuf[buf]; char* vb_ = (char*)VsBuf[buf]; \
        _Pragma("unroll") \
        for (int j = 0; j < 4; ++j) { \
            gload16(kg_ + srcK[j], kb_ + (tid + 128 * j) * 16); \
            gload16(vg_ + srcV[j], vb_ + (tid + 128 * j) * 16); } } while (0)

    bf16x8 qf[4];
    {
        const __hip_bfloat16* qp = Q + bho + (size_t)(qw + l31) * HS + hi * 8;
#pragma unroll
        for (int kb = 0; kb < 4; ++kb) qf[kb] = *(const bf16x8*)(qp + kb * 16);
    }
    const int base0 = l31 * 128;
    const int swz0 = ((l31 ^ (l31 >> 3)) & 7) << 4;
    const int r32 = 32 + l31;
    const int base1 = r32 * 128;
    const int swz1 = ((r32 ^ (r32 >> 3)) & 7) << 4;

    float mrow = -1e30f, lsum = 0.f;
    f32x16 o0 = {}, o1 = {};

    ASTAGE(0, 0);
    __syncthreads();
    for (int kt = 0; kt <= qb; ++kt) {
        const int cur = kt & 1;
        if (kt < qb) ASTAGE(cur ^ 1, kt + 1);
        const char* KsB = (const char*)KsBuf[cur];
        const char* VsB = (const char*)VsBuf[cur];
        const bool do1 = (w == 1) || (kt < qb);
        f32x16 s0 = {}, s1 = {};
        __builtin_amdgcn_s_setprio(1);
#pragma unroll
        for (int kb = 0; kb < 4; ++kb) {
            bf16x8 kf = *(const bf16x8*)(KsB + base0 + ((kb * 32 + hi * 16) ^ swz0));
            s0 = __builtin_amdgcn_mfma_f32_32x32x16_bf16(kf, qf[kb], s0, 0, 0, 0);
        }
        if (do1) {
#pragma unroll
            for (int kb = 0; kb < 4; ++kb) {
                bf16x8 kf = *(const bf16x8*)(KsB + base1 + ((kb * 32 + hi * 16) ^ swz1));
                s1 = __builtin_amdgcn_mfma_f32_32x32x16_bf16(kf, qf[kb], s1, 0, 0, 0);
            }
        }
        __builtin_amdgcn_s_setprio(0);
        if (kt == qb) {
            if (w == 0) {
#pragma unroll
                for (int r = 0; r < 16; ++r) {
                    int crow = (r & 3) + 8 * (r >> 2) + 4 * hi;
                    if (crow > l31) s0[r] = -1e30f;
                }
            } else {
#pragma unroll
                for (int r = 0; r < 16; ++r) {
                    int crow = (r & 3) + 8 * (r >> 2) + 4 * hi;
                    if (crow > l31) s1[r] = -1e30f;
                }
            }
        }
        float mx = s0[0];
#pragma unroll
        for (int r = 1; r < 16; ++r) mx = fmaxf(mx, s0[r]);
        if (do1) {
#pragma unroll
            for (int r = 0; r < 16; ++r) mx = fmaxf(mx, s1[r]);
        }
        mx = fmaxf(mx, __shfl_xor(mx, 32));
        const float mn = fmaxf(mrow, mx);
        const float alpha = __builtin_amdgcn_exp2f(mrow - mn);
        mrow = mn;
        float ls = 0.f;
#pragma unroll
        for (int r = 0; r < 16; ++r) { s0[r] = __builtin_amdgcn_exp2f(s0[r] - mn); ls += s0[r]; }
        if (do1) {
#pragma unroll
            for (int r = 0; r < 16; ++r) { s1[r] = __builtin_amdgcn_exp2f(s1[r] - mn); ls += s1[r]; }
        }
        ls += __shfl_xor(ls, 32);
        lsum = lsum * alpha + ls;
        o0 = o0 * alpha;
        o1 = o1 * alpha;
        union { u32 u[4]; bf16x8 v; } pa[4];
        {
            u32 w01 = pk2(s0[0], s0[1]),   w23 = pk2(s0[2], s0[3]);
            u32 w45 = pk2(s0[4], s0[5]),   w67 = pk2(s0[6], s0[7]);
            u32 w89 = pk2(s0[8], s0[9]),   wab = pk2(s0[10], s0[11]);
            u32 wcd = pk2(s0[12], s0[13]), wef = pk2(s0[14], s0[15]);
            u32 xa = __shfl_xor(hi ? w01 : w45, 32);
            u32 xb = __shfl_xor(hi ? w23 : w67, 32);
            u32 xc = __shfl_xor(hi ? w89 : wcd, 32);
            u32 xd = __shfl_xor(hi ? wab : wef, 32);
            if (hi == 0) {
                pa[0].u[0] = w01; pa[0].u[1] = w23; pa[0].u[2] = xa;  pa[0].u[3] = xb;
                pa[1].u[0] = w89; pa[1].u[1] = wab; pa[1].u[2] = xc;  pa[1].u[3] = xd;
            } else {
                pa[0].u[0] = xa;  pa[0].u[1] = xb;  pa[0].u[2] = w45; pa[0].u[3] = w67;
                pa[1].u[0] = xc;  pa[1].u[1] = xd;  pa[1].u[2] = wcd; pa[1].u[3] = wef;
            }
        }
        if (do1) {
            u32 w01 = pk2(s1[0], s1[1]),   w23 = pk2(s1[2], s1[3]);
            u32 w45 = pk2(s1[4], s1[5]),   w67 = pk2(s1[6], s1[7]);
            u32 w89 = pk2(s1[8], s1[9]),   wab = pk2(s1[10], s1[11]);
            u32 wcd = pk2(s1[12], s1[13]), wef = pk2(s1[14], s1[15]);
            u32 xa = __shfl_xor(hi ? w01 : w45, 32);
            u32 xb = __shfl_xor(hi ? w23 : w67, 32);
            u32 xc = __shfl_xor(hi ? w89 : wcd, 32);
            u32 xd = __shfl_xor(hi ? wab : wef, 32);
            if (hi == 0) {
                pa[2].u[0] = w01; pa[2].u[1] = w23; pa[2].u[2] = xa;  pa[2].u[3] = xb;
                pa[3].u[0] = w89; pa[3].u[1] = wab; pa[3].u[2] = xc;  pa[3].u[3] = xd;
            } else {
                pa[2].u[0] = xa;  pa[2].u[1] = xb;  pa[2].u[2] = w45; pa[2].u[3] = w67;
                pa[3].u[0] = xc;  pa[3].u[1] = xd;  pa[3].u[2] = wcd; pa[3].u[3] = wef;
            }
        }
        __builtin_amdgcn_s_setprio(1);
#pragma unroll
        for (int ks = 0; ks < 2; ++ks) {
            bf16x8 vf0 = *(const bf16x8*)(VsB + base0 + ((ks * 32 + hi * 16) ^ swz0));
            o0 = __builtin_amdgcn_mfma_f32_32x32x16_bf16(vf0, pa[ks].v, o0, 0, 0, 0);
            bf16x8 vf1 = *(const bf16x8*)(VsB + base1 + ((ks * 32 + hi * 16) ^ swz1));
            o1 = __builtin_amdgcn_mfma_f32_32x32x16_bf16(vf1, pa[ks].v, o1, 0, 0, 0);
        }
        if (do1) {
#pragma unroll
            for (int ks = 2; ks < 4; ++ks) {
                bf16x8 vf0 = *(const bf16x8*)(VsB + base0 + ((ks * 32 + hi * 16) ^ swz0));
                o0 = __builtin_amdgcn_mfma_f32_32x32x16_bf16(vf0, pa[ks].v, o0, 0, 0, 0);
                bf16x8 vf1 = *(const bf16x8*)(VsB + base1 + ((ks * 32 + hi * 16) ^ swz1));
                o1 = __builtin_amdgcn_mfma_f32_32x32x16_bf16(vf1, pa[ks].v, o1, 0, 0, 0);
            }
        }
        __builtin_amdgcn_s_setprio(0);
        __syncthreads();
    }
    __syncthreads();
    {
        char* T = (char*)KsBuf[0] + w * 4096;
        const float inv = 1.f / lsum;
        const int tsw = (l31 & 7) << 4;
#pragma unroll
        for (int r = 0; r < 16; ++r) {
            int d0 = (r & 3) + 8 * (r >> 2) + 4 * hi;
            *(__hip_bfloat16*)(T + base0 + ((d0 * 2) ^ tsw)) = __float2bfloat16(o0[r] * inv);
            *(__hip_bfloat16*)(T + base0 + (((d0 + 32) * 2) ^ tsw)) = __float2bfloat16(o1[r] * inv);
        }
        const int b = bh >> 4, h = bh & 15;
#pragma unroll
        for (int p = 0; p < 4; ++p) {
            int q = p * 8 + (lane >> 3);
            int colb = ((lane & 7) * 16) ^ ((q & 7) << 4);
            bf16x8 v = *(const bf16x8*)(T + q * 128 + colb);
            *(bf16x8*)(Y + ((size_t)b * TSEQ + qw + q) * CEMB + h * HS + (lane & 7) * 8) = v;
        }
    }
#undef ASTAGE
}

// ---------------- Output projection, bf16 MFMA ----------------
__global__ __launch_bounds__(256) void proj_mfma_k(
    const __hip_bfloat16* __restrict__ Ab, const __hip_bfloat16* __restrict__ Wt,
    const float* __restrict__ bias, float* __restrict__ out)
{
    __shared__ __hip_bfloat16 Al[2][128 * 32];
    __shared__ __hip_bfloat16 Bl[2][128 * 32];
    const int tid = threadIdx.x;
    const int lane = tid & 63, w = tid >> 6;
    const int lr = lane & 15, lg = lane >> 4;
    const int wm = w >> 1, wn = w & 1;
    const int n0 = blockIdx.x * 128;
    const int m0 = blockIdx.y * 128;
    const __hip_bfloat16* gA = Ab + (size_t)(m0 + (tid >> 2)) * CEMB + (tid & 3) * 8;
    const __hip_bfloat16* gB = Wt + (size_t)(n0 + (tid >> 2)) * CEMB + (tid & 3) * 8;
#define PSTAGE(buf, kk) do { \
        gload16(gA + (kk), &Al[buf][tid * 8]); \
        gload16(gA + 64 * CEMB + (kk), &Al[buf][2048 + tid * 8]); \
        gload16(gB + (kk), &Bl[buf][tid * 8]); \
        gload16(gB + 64 * CEMB + (kk), &Bl[buf][2048 + tid * 8]); } while (0)
    f32x4 acc[4][4] = {};
    PSTAGE(0, 0);
    __syncthreads();
    for (int k0 = 0; k0 < CEMB; k0 += 32) {
        const int cur = (k0 >> 5) & 1;
        if (k0 + 32 < CEMB) PSTAGE(cur ^ 1, k0 + 32);
        bf16x8 af[4], bfr[4];
#pragma unroll
        for (int mi = 0; mi < 4; ++mi)
            af[mi] = *(const bf16x8*)&Al[cur][(wm * 64 + mi * 16 + lr) * 32 + lg * 8];
#pragma unroll
        for (int ni = 0; ni < 4; ++ni)
            bfr[ni] = *(const bf16x8*)&Bl[cur][(wn * 64 + ni * 16 + lr) * 32 + lg * 8];
#pragma unroll
        for (int mi = 0; mi < 4; ++mi)
#pragma unroll
            for (int ni = 0; ni < 4; ++ni)
                acc[mi][ni] = __builtin_amdgcn_mfma_f32_16x16x32_bf16(af[mi], bfr[ni], acc[mi][ni], 0, 0, 0);
        __syncthreads();
    }
#pragma unroll
    for (int mi = 0; mi < 4; ++mi) {
#pragma unroll
        for (int ni = 0; ni < 4; ++ni) {
            const int gcol = n0 + wn * 64 + ni * 16 + lr;
            const float bv = bias[gcol];
            const int growb = m0 + wm * 64 + mi * 16 + lg * 4;
#pragma unroll
            for (int r = 0; r < 4; ++r)
                out[(size_t)(growb + r) * CEMB + gcol] = acc[mi][ni][r] + bv;
        }
    }
#undef PSTAGE
}

extern "C" void kernel_launch(void* const* d_in, const int* in_sizes, int n_in,
                              void* d_out, int out_size, void* d_ws, size_t ws_size,
                              hipStream_t stream)
{
    const float* x      = (const float*)d_in[0];
    const float* w_attn = (const float*)d_in[1];
    const float* b_attn = (const float*)d_in[2];
    const float* w_proj = (const float*)d_in[3];
    const float* b_proj = (const float*)d_in[4];
    float* out = (float*)d_out;
    char* base = (char*)d_ws;

    const size_t MB = 1048576;
    float* tbl          = (float*)base;                         // 4 KB
    __hip_bfloat16* Xb  = (__hip_bfloat16*)(base + 4096);       // 8 MB (reused as Yb)
    __hip_bfloat16* Wta = (__hip_bfloat16*)(base + 4096 + 8 * MB);   // 6 MB
    __hip_bfloat16* Wpt = (__hip_bfloat16*)(base + 4096 + 14 * MB);  // 2 MB
    __hip_bfloat16* Qb  = (__hip_bfloat16*)(base + 4096 + 16 * MB);  // 8 MB
    __hip_bfloat16* Kb  = (__hip_bfloat16*)(base + 4096 + 24 * MB);  // 8 MB
    __hip_bfloat16* Vtb = (__hip_bfloat16*)(base + 4096 + 32 * MB);  // 8 MB
    __hip_bfloat16* Yb  = Xb;   // x no longer needed after qkv GEMM

    rope_tbl_k<<<1, 512, 0, stream>>>(tbl);
    cvt_bf16_k<<<2048, 256, 0, stream>>>(x, Xb);
    transpose_bf16_k<<<dim3(96, 32), 256, 0, stream>>>(w_attn, Wta, CEMB, 3 * CEMB);
    transpose_bf16_k<<<dim3(32, 32), 256, 0, stream>>>(w_proj, Wpt, CEMB, CEMB);
    qkv_mfma_k<<<dim3(24, 32), 256, 0, stream>>>(Xb, Wta, b_attn, tbl, Qb, Kb, Vtb);
    attn_k<<<1024, 128, 0, stream>>>(Qb, Kb, Vtb, Yb);
    proj_mfma_k<<<dim3(8, 32), 256, 0, stream>>>(Yb, Wpt, b_proj, out);
}